// Round 5
// baseline (117.670 us; speedup 1.0000x reference)
//
#include <hip/hip_runtime.h>

// CTC loss forward, f64 prob-domain with power-of-2 rescaling.
// v6: fwd/bwd separate blocks (v5) + 8-WAY STATE SPLIT, 2 states/lane.
// v5 post-mortem: fb kernel ~190 cy/step wall vs ~72-95 cy issue -- >50%
// dependency stall with 1 wave/SIMD (every stall is dead time). v4 proved
// 2 FULL-work waves/SIMD saturate the f64 VALU pipe; v6 keeps per-SIMD
// demand constant: per-wave work halves (2 states/lane), 8 waves/block,
// 2 waves/SIMD interleave to fill each other's stalls.
// Regions: 128 states/wave. fwd: wl=0 owns [0,128) (true bottom boundary,
// exact); wl>=1 owns [64wl+64,64wl+128), pad [64wl,64wl+64) below absorbs
// 2/step x 32-step contamination, refreshed from owner each chunk. bwd
// mirrored: wl=7 exact (states >512 stay 0 inductively), wl<7 owns bottom
// 64, pad above. Per-state FP op ORDER identical to v5 -> bit-identical
// alpha/beta -> absmax 0.
// Harness-cost model (discovered r4): dur ~= our kernels + ~60us fixed
// (fillBufferAligned 46us = mandatory d_ws poison + ~15us launch). ws use
// is free; only kernel time matters.
// ws layout (doubles) per b, stride 1028: [0..512] alphaF, [513] toteF,
// [514..1026] betaB, [1027] toteB.

#define Bc 64
#define Tc 1024
#define Cc 128
#define Lc 256
#define Sc 513
#define BLANKc 127
#define CHUNK 32
#define NW 8
#define WSSTRIDE 1028

constexpr float EPSF = 1e-7f;

#define DPPMAXI(x, ctrl) max(x, __builtin_amdgcn_update_dpp( \
    0, x, ctrl, 0xf, 0xf, true))

__device__ __forceinline__ double dpp_wave_shr1_f64(double x) {
    // lane l <- lane l-1; lane 0 <- 0 (bound_ctrl)
    union { double d; int i[2]; } u, r;
    u.d = x;
    r.i[0] = __builtin_amdgcn_update_dpp(0, u.i[0], 0x138, 0xf, 0xf, true);
    r.i[1] = __builtin_amdgcn_update_dpp(0, u.i[1], 0x138, 0xf, 0xf, true);
    return r.d;
}
__device__ __forceinline__ double dpp_wave_shl1_f64(double x) {
    // lane l <- lane l+1; lane 63 <- 0 (bound_ctrl)
    union { double d; int i[2]; } u, r;
    u.d = x;
    r.i[0] = __builtin_amdgcn_update_dpp(0, u.i[0], 0x130, 0xf, 0xf, true);
    r.i[1] = __builtin_amdgcn_update_dpp(0, u.i[1], 0x130, 0xf, 0xf, true);
    return r.d;
}

__global__ __launch_bounds__(512) void ctc_fb_kernel(
    const int* __restrict__ y_true,        // [B, L]
    const float* __restrict__ y_pred,      // [B, T, C]
    const int* __restrict__ label_length,  // [B, 1]
    double* __restrict__ ws)
{
    const int bb = blockIdx.x;
    const int b = bb >> 1;
    const bool isF = !(bb & 1);
    const int tid = (int)threadIdx.x;
    const int wl = tid >> 6;               // wave 0..7
    const int lane = tid & 63;

    __shared__ float bufs[3][CHUNK * Cc];  // 3 x 16 KB staged y_pred rows
    __shared__ double ash[Sc];             // owned-alpha/beta exchange
    __shared__ int em[NW];                 // per-wave masked exponent max

    const int lab_len = label_length[b];
    const float* yp = y_pred + (size_t)b * Tc * Cc;
    const int* lab = y_true + b * Lc;
    double* wsb = ws + (size_t)b * WSSTRIDE;

    // ---- region geometry: region = [64wl, 64wl+128), 2 states/lane ----
    const int start = 64 * wl;
    const int s0 = start + 2 * lane;       // even; lane holds s0, s0+1
    const int own_s = isF ? ((wl == 0) ? 0 : (start + 64)) : start;
    const int own_e = isF ? min(start + 128, Sc)
                          : ((wl == NW - 1) ? Sc : (start + 64));

    // ---- per-lane static metadata ----
    const int li0 = s0 >> 1;               // label idx of state s0+1
    const int li0c = min(li0, Lc - 1);
    const int li1c = min(li0 + 1, Lc - 1);
    const int ca = lab[li0c], cb = lab[li1c];
    const double sm_a = (li0 > 0 && ca != BLANKc && ca != lab[li0c - 1]) ? 1.0 : 0.0;
    const double sm_b = (cb != BLANKc && cb != ca) ? 1.0 : 0.0;

    const int S2 = 2 * lab_len + 1;
    const bool ow0 = (s0     >= own_s) && (s0     < own_e);
    const bool ow1 = (s0 + 1 >= own_s) && (s0 + 1 < own_e);
    const int om0 = (ow0 && s0     < S2) ? -1 : 0;
    const int om1 = (ow1 && s0 + 1 < S2) ? -1 : 0;

    // ---- staging: each wave DMAs its eighth (2 KB) of a 16 KB chunk ----
    auto stage = [&](int c, float* dst) {
        const float* g = yp + (size_t)c * (CHUNK * Cc) + lane * 4;
        #pragma unroll
        for (int q = 0; q < 2; ++q) {
            const int i = wl * 2 + q;
            __builtin_amdgcn_global_load_lds(
                (const __attribute__((address_space(1))) void*)(g + i * 256),
                (__attribute__((address_space(3))) void*)(dst + i * 256),
                16, 0, 0);
        }
    };

    if (isF) {
        // =================== FORWARD: rows 0 .. 511 ===================
        double a0 = 0, a1 = 0, n1 = 0;     // n1 = pipelined shr(a1)
        int tote = 0;
        double Eb, Ea;                     // even-row p: blank, ca
        double Ob, Oa;                     // odd-row p
        float sl[4][4];                    // pair P in sl[P&3], gathered 3 ahead

        auto gpair = [&](const float* rowp, float* s) {
            s[0] = rowp[BLANKc]; s[1] = rowp[BLANKc + Cc];
            s[2] = rowp[ca];     s[3] = rowp[ca + Cc];
        };
        auto expandE = [&](const float* s) {
            Eb = (double)(s[0] + EPSF); Ea = (double)(s[2] + EPSF);
        };
        auto expandO = [&](const float* s) {
            Ob = (double)(s[1] + EPSF); Oa = (double)(s[3] + EPSF);
        };
        auto stepE = [&]() {
            const double t1 = __fma_rn(sm_a, n1, a1 + a0);
            const double t0 = a0 + n1;
            a1 = t1 * Ea;
            n1 = dpp_wave_shr1_f64(a1);
            a0 = t0 * Eb;
        };
        auto stepO = [&]() {
            const double t1 = __fma_rn(sm_a, n1, a1 + a0);
            const double t0 = a0 + n1;
            a1 = t1 * Oa;
            n1 = dpp_wave_shr1_f64(a1);
            a0 = t0 * Ob;
        };
        auto syncex = [&](int sk) {
            int e =        om0 & (__double2hiint(a0) >> 20);
            e = max(e, om1 & (__double2hiint(a1) >> 20));
            e = DPPMAXI(e, 0x111); e = DPPMAXI(e, 0x112);
            e = DPPMAXI(e, 0x114); e = DPPMAXI(e, 0x118);
            e = DPPMAXI(e, 0x142); e = DPPMAXI(e, 0x143);
            if (lane == 63) em[wl] = e;
            if (ow0) ash[s0]     = a0;
            if (ow1) ash[s0 + 1] = a1;
            __syncthreads();               // barrier 1 (drains lgkm + vm)
            int eg = em[0];
            #pragma unroll
            for (int w = 1; w < NW; ++w) eg = max(eg, em[w]);
            const int sexp = min(max(2046 - eg, 1), 2045);
            const double sc = __hiloint2double(sexp << 20, 0);
            tote += 1023 - sexp;
            if (wl > 0 && lane < 32) {     // refresh pad from below-owner
                a0 = ash[s0]; a1 = ash[s0 + 1];
            }
            a0 *= sc; a1 *= sc;
            n1 = dpp_wave_shr1_f64(a1);
            __syncthreads();               // barrier 2 (ash/em reuse safe)
            if (sk <= 15) stage(sk, bufs[sk % 3]);  // DMA after barrier
        };

        // ---- prologue ----
        stage(0, bufs[0]); stage(1, bufs[1]); stage(2, bufs[2]);
        __syncthreads();

        if (wl == 0 && lane == 0) {
            a0 = (double)(bufs[0][BLANKc] + EPSF);               // s=0
            if (lab_len > 0) a1 = (double)(bufs[0][ca] + EPSF);  // s=1
        }
        gpair(bufs[0] + 2 * Cc, sl[1]);
        gpair(bufs[0] + 4 * Cc, sl[2]);
        gpair(bufs[0] + 6 * Cc, sl[3]);
        {
            const float* r1 = bufs[0] + 1 * Cc;
            Ob = (double)(r1[BLANKc] + EPSF);
            Oa = (double)(r1[ca] + EPSF);
        }
        expandE(sl[1]);                    // row 2

        stepO();                           // lone step t=1
        expandO(sl[1]);                    // row 3

        // chunk 0: pairs 1..15 (rows 2..31)
        {
            const float* rb  = bufs[0];
            const float* rbn = bufs[1];
            #pragma unroll
            for (int qi = 1; qi < 16; ++qi) {
                const int rr = 2 * qi;
                const float* nxt = (rr + 6 < CHUNK) ? (rb + (rr + 6) * Cc)
                                                    : (rbn + (rr + 6 - CHUNK) * Cc);
                gpair(nxt, sl[(qi + 3) & 3]);
                stepE();
                expandE(sl[(qi + 1) & 3]);
                stepO();
                expandO(sl[(qi + 1) & 3]);
            }
        }
        // chunks 1..15 (rows 32..511)
        for (int k = 1; k < 16; ++k) {
            syncex(k + 2);
            const float* rb  = bufs[k % 3];
            const float* rbn = bufs[(k + 1) % 3];   // k=15: dead reads, safe
            #pragma unroll
            for (int qi = 0; qi < 16; ++qi) {
                const int rr = 2 * qi;
                const float* nxt = (rr + 6 < CHUNK) ? (rb + (rr + 6) * Cc)
                                                    : (rbn + (rr + 6 - CHUNK) * Cc);
                gpair(nxt, sl[(qi + 3) & 3]);
                stepE();
                expandE(sl[(qi + 1) & 3]);
                stepO();
                expandO(sl[(qi + 1) & 3]);
            }
        }
        // publish alpha_511 (pre-rescale) + toteF
        if (ow0) wsb[s0]     = a0;
        if (ow1) wsb[s0 + 1] = a1;
        if (tid == 0) wsb[513] = (double)tote;
    } else {
        // =================== BACKWARD: rows 1023 .. 512 ===================
        // beta'(s) = sum_{s' in {s, s+1, s+2*sk}} p_t(s') * beta(s')
        double b0 = 0, b1 = 0, n0 = 0, n1 = 0;  // n0=shl(b0), n1=shl(b1)
        int tote = 0;
        double Eb, Ea, Ec;                 // even-row p: blank, ca, cb
        double Ob, Oa, Oc;                 // odd-row p
        float sl[4][6];

        auto gpair = [&](const float* rowp, float* s) {
            s[0] = rowp[BLANKc]; s[1] = rowp[BLANKc + Cc];
            s[2] = rowp[ca];     s[3] = rowp[ca + Cc];
            s[4] = rowp[cb];     s[5] = rowp[cb + Cc];
        };
        auto expandE = [&](const float* s) {
            Eb = (double)(s[0] + EPSF); Ea = (double)(s[2] + EPSF);
            Ec = (double)(s[4] + EPSF);
        };
        auto expandO = [&](const float* s) {
            Ob = (double)(s[1] + EPSF); Oa = (double)(s[3] + EPSF);
            Oc = (double)(s[5] + EPSF);
        };
        // state s0 (even): Eb*b0 + Ea*b1
        // state s0+1 (odd): (Ea*b1 + Eb*b(s0+2)) + sm_b*(Ec*b(s0+3))
        //   b(s0+2)=n0, b(s0+3)=n1 (lane l+1's b0,b1). Op order == v5.
        auto stepBE = [&]() {
            const double x1 = Ea * b1, x2 = Eb * n0, x3 = Ec * n1;
            const double r0 = __fma_rn(Eb, b0, x1);
            const double r1 = __fma_rn(sm_b, x3, x1 + x2);
            b0 = r0; b1 = r1;
            n0 = dpp_wave_shl1_f64(b0);
            n1 = dpp_wave_shl1_f64(b1);
        };
        auto stepBO = [&]() {
            const double x1 = Oa * b1, x2 = Ob * n0, x3 = Oc * n1;
            const double r0 = __fma_rn(Ob, b0, x1);
            const double r1 = __fma_rn(sm_b, x3, x1 + x2);
            b0 = r0; b1 = r1;
            n0 = dpp_wave_shl1_f64(b0);
            n1 = dpp_wave_shl1_f64(b1);
        };
        auto syncex = [&](int sk) {
            int e =        om0 & (__double2hiint(b0) >> 20);
            e = max(e, om1 & (__double2hiint(b1) >> 20));
            e = DPPMAXI(e, 0x111); e = DPPMAXI(e, 0x112);
            e = DPPMAXI(e, 0x114); e = DPPMAXI(e, 0x118);
            e = DPPMAXI(e, 0x142); e = DPPMAXI(e, 0x143);
            if (lane == 63) em[wl] = e;
            if (ow0) ash[s0]     = b0;
            if (ow1) ash[s0 + 1] = b1;
            __syncthreads();               // barrier 1
            int eg = em[0];
            #pragma unroll
            for (int w = 1; w < NW; ++w) eg = max(eg, em[w]);
            const int sexp = min(max(2046 - eg, 1), 2045);
            const double sc = __hiloint2double(sexp << 20, 0);
            tote += 1023 - sexp;
            // refresh pad above from owner; zero beyond S space
            if (s0     >= own_e) b0 = (s0     < Sc) ? ash[s0]     : 0.0;
            if (s0 + 1 >= own_e) b1 = (s0 + 1 < Sc) ? ash[s0 + 1] : 0.0;
            b0 *= sc; b1 *= sc;
            n0 = dpp_wave_shl1_f64(b0);
            n1 = dpp_wave_shl1_f64(b1);
            __syncthreads();               // barrier 2
            if (sk >= 16) stage(sk, bufs[(31 - sk) % 3]);
        };

        // ---- prologue: chunks 31,30,29 -> bufs 0,1,2 ----
        stage(31, bufs[0]); stage(30, bufs[1]); stage(29, bufs[2]);
        __syncthreads();

        // init beta_{1023}: 1 at end states {2L, 2L-1}
        {
            const int e0 = 2 * lab_len;
            const int e1 = (lab_len > 0) ? (2 * lab_len - 1) : e0;
            b0 = (s0     == e0 || s0     == e1) ? 1.0 : 0.0;
            b1 = (s0 + 1 == e0 || s0 + 1 == e1) ? 1.0 : 0.0;
            n0 = dpp_wave_shl1_f64(b0);
            n1 = dpp_wave_shl1_f64(b1);
        }
        // prime chunk 31 (bufs[0]): pairs 15,14,13 -> slots 3,2,1
        gpair(bufs[0] + 30 * Cc, sl[3]);
        gpair(bufs[0] + 28 * Cc, sl[2]);
        gpair(bufs[0] + 26 * Cc, sl[1]);
        expandO(sl[3]);                    // row 31 (abs t=1023)
        expandE(sl[3]);                    // row 30

        // chunk 31: q = 15..0 (rows descend; odd step first per pair)
        {
            const float* rb  = bufs[0];
            const float* rbn = bufs[1];    // chunk 30
            #pragma unroll
            for (int j = 0; j < 16; ++j) {
                const int q = 15 - j;
                const int rr = 2 * q;
                const float* nxt = (rr - 6 >= 0) ? (rb + (rr - 6) * Cc)
                                                 : (rbn + (rr - 6 + CHUNK) * Cc);
                gpair(nxt, sl[(q + 1) & 3]);   // pair q-3 (3 ahead in order)
                stepBO();
                expandO(sl[(q - 1) & 3]);
                stepBE();
                expandE(sl[(q - 1) & 3]);
            }
        }
        // chunks 30..16
        for (int c = 30; c >= 16; --c) {
            syncex(c - 2);
            const float* rb  = bufs[(31 - c) % 3];
            const float* rbn = bufs[(32 - c) % 3];  // c=16: dead reads, safe
            #pragma unroll
            for (int j = 0; j < 16; ++j) {
                const int q = 15 - j;
                const int rr = 2 * q;
                const float* nxt = (rr - 6 >= 0) ? (rb + (rr - 6) * Cc)
                                                 : (rbn + (rr - 6 + CHUNK) * Cc);
                gpair(nxt, sl[(q + 1) & 3]);
                stepBO();
                expandO(sl[(q - 1) & 3]);
                stepBE();
                expandE(sl[(q - 1) & 3]);
            }
        }
        // publish beta_511 (pre-rescale) + toteB
        if (ow0) wsb[514 + s0]     = b0;
        if (ow1) wsb[514 + s0 + 1] = b1;
        if (tid == 0) wsb[1027] = (double)tote;
    }
}

__global__ __launch_bounds__(64) void ctc_combine(
    const int* __restrict__ label_length,
    const double* __restrict__ ws,
    float* __restrict__ out)
{
    const int b = blockIdx.x;
    const int lane = (int)threadIdx.x;
    const int lab_len = label_length[b];
    const int S2 = 2 * lab_len + 1;
    const double* wf = ws + (size_t)b * WSSTRIDE;
    const double* wb = wf + 514;

    int eP = 0;                            // max biased-exponent sum of products
    for (int s = lane; s < S2; s += 64) {
        const int ea = (__double2hiint(wf[s]) >> 20) & 0x7ff;
        const int eb = (__double2hiint(wb[s]) >> 20) & 0x7ff;
        if (ea && eb) eP = max(eP, ea + eb);
    }
    #pragma unroll
    for (int m = 1; m < 64; m <<= 1) eP = max(eP, __shfl_xor(eP, m));
    const int sh = 2046 - eP;
    int k1 = sh / 2;
    int k2 = sh - k1;
    k1 = min(max(k1, -1022), 1023);
    k2 = min(max(k2, -1022), 1023);
    const double scA = __hiloint2double((1023 + k1) << 20, 0);
    const double scB = __hiloint2double((1023 + k2) << 20, 0);
    double dot = 0.0;
    for (int s = lane; s < S2; s += 64)
        dot += (wf[s] * scA) * (wb[s] * scB);
    #pragma unroll
    for (int m = 1; m < 64; m <<= 1) dot += __shfl_xor(dot, m);
    if (lane == 0) {
        const double lt = wf[513] + wb[513] - (double)k1 - (double)k2;
        out[b] = (float)(-(log(dot) + lt * 0.6931471805599453));
    }
}

extern "C" void kernel_launch(void* const* d_in, const int* in_sizes, int n_in,
                              void* d_out, int out_size, void* d_ws, size_t ws_size,
                              hipStream_t stream) {
    const int*   y_true       = (const int*)d_in[0];
    const float* y_pred       = (const float*)d_in[1];
    const int*   label_length = (const int*)d_in[3];
    float* out = (float*)d_out;
    double* ws = (double*)d_ws;

    ctc_fb_kernel<<<2 * Bc, NW * 64, 0, stream>>>(y_true, y_pred,
                                                  label_length, ws);
    ctc_combine<<<Bc, 64, 0, stream>>>(label_length, ws, out);
}